// Round 6
// baseline (50505.682 us; speedup 1.0000x reference)
//
#include <hip/hip_runtime.h>
#include <hip/hip_fp16.h>
#include <cstddef>
#include <cstdint>

// Problem constants (from reference)
#define NB   64      // B
#define TB   512     // T
#define FB   512     // F
#define NPOI 100000

union U4 { uint4 u; __half2 h[4]; };

// ---------------------------------------------------------------------------
// 1. Pack Whh (fp32, [L][g][f]) into fp16 pack-slots for the scan.
//    Thread-slot tid: q=tid&3 owns f-slice [128q,128q+128), rows g0..g0+3
//    (g0 = tid&~3). Pack j layout (per layer, [64][512] uint4):
//      j in [0,48):  register packs: gi=j/12, k=j%12, f0=8k      (f local 0..96)
//      j in [48,64): stream packs:   s=j-48, gi=s&3, f0=96+8*(s>>2)
//    Each uint4 = 4 __half2 = 8 consecutive f-values of one row.
// ---------------------------------------------------------------------------
__global__ __launch_bounds__(512)
void k_pack(const float* __restrict__ Whh, uint4* __restrict__ wp)
{
    const int j = blockIdx.x, l = blockIdx.y, tid = threadIdx.x;
    int gi, f0;
    if (j < 48) { gi = j / 12; f0 = 8 * (j % 12); }
    else        { const int s = j - 48; gi = s & 3; f0 = 96 + 8 * (s >> 2); }
    const int g = (tid & ~3) + gi;
    const int f = 128 * (tid & 3) + f0;
    const float* src = Whh + (size_t)l * FB * FB + (size_t)g * FB + f;
    const float4 a = *(const float4*)src;
    const float4 b = *(const float4*)(src + 4);
    U4 o;
    o.h[0] = __floats2half2_rn(a.x, a.y);
    o.h[1] = __floats2half2_rn(a.z, a.w);
    o.h[2] = __floats2half2_rn(b.x, b.y);
    o.h[3] = __floats2half2_rn(b.z, b.w);
    wp[((size_t)l * 64 + j) * 512 + tid] = o.u;
}

// ---------------------------------------------------------------------------
// 2. Generic fp32 GEMM: C[M,N] = A[M,K] @ B[N,K]^T + bias[N]  (unchanged)
// ---------------------------------------------------------------------------
template<bool EMBED, bool DUAL>
__global__ __launch_bounds__(256)
void k_gemm_bt(const float* __restrict__ A,
               const int* __restrict__ uidx, const int* __restrict__ pidx,
               const float* __restrict__ utab, const float* __restrict__ ptab,
               const float* __restrict__ Bm, const float* __restrict__ bias,
               float* __restrict__ C, float* __restrict__ C2,
               int M, int N, int K)
{
    __shared__ __align__(16) float As[16][68];
    __shared__ __align__(16) float Bs[16][68];
    __shared__ int us[64], ps[64];

    const int tid = threadIdx.x;
    const int tn  = tid & 15, tm = tid >> 4;
    const int m0  = blockIdx.y * 64, n0 = blockIdx.x * 64;
    const int lr  = tid >> 2;
    const int lc  = (tid & 3) * 4;

    if (EMBED) {
        if (tid < 64) { us[tid] = uidx[m0 + tid]; ps[tid] = pidx[m0 + tid]; }
        __syncthreads();
    }

    float acc[4][4] = {};

    for (int k0 = 0; k0 < K; k0 += 16) {
        float4 a4, b4;
        if (EMBED) {
            const float4 u4 = *(const float4*)&utab[(size_t)us[lr] * K + k0 + lc];
            const float4 p4 = *(const float4*)&ptab[(size_t)ps[lr] * K + k0 + lc];
            a4 = make_float4(u4.x + p4.x, u4.y + p4.y, u4.z + p4.z, u4.w + p4.w);
        } else {
            a4 = *(const float4*)&A[(size_t)(m0 + lr) * K + k0 + lc];
        }
        const int nr = n0 + lr;
        if (nr < N) b4 = *(const float4*)&Bm[(size_t)nr * K + k0 + lc];
        else        b4 = make_float4(0.f, 0.f, 0.f, 0.f);

        __syncthreads();
        As[lc + 0][lr] = a4.x; As[lc + 1][lr] = a4.y;
        As[lc + 2][lr] = a4.z; As[lc + 3][lr] = a4.w;
        Bs[lc + 0][lr] = b4.x; Bs[lc + 1][lr] = b4.y;
        Bs[lc + 2][lr] = b4.z; Bs[lc + 3][lr] = b4.w;
        __syncthreads();

        #pragma unroll
        for (int kk = 0; kk < 16; ++kk) {
            const float4 av4 = *(const float4*)&As[kk][tm * 4];
            const float4 bv4 = *(const float4*)&Bs[kk][tn * 4];
            const float av[4] = {av4.x, av4.y, av4.z, av4.w};
            const float bv[4] = {bv4.x, bv4.y, bv4.z, bv4.w};
            #pragma unroll
            for (int i = 0; i < 4; ++i)
                #pragma unroll
                for (int j = 0; j < 4; ++j)
                    acc[i][j] += av[i] * bv[j];
        }
    }

    const int cm = m0 + tm * 4, cn = n0 + tn * 4;
    #pragma unroll
    for (int i = 0; i < 4; ++i) {
        #pragma unroll
        for (int j = 0; j < 4; ++j) {
            const int n = cn + j;
            if (n < N) {
                const float v = acc[i][j] + bias[n];
                C[(size_t)(cm + i) * N + n] = v;
                if (DUAL) C2[(size_t)(cm + i) * N + n] = v;
            }
        }
    }
}

// ---------------------------------------------------------------------------
// 3. RNN scan, blocked 4g x 128f per thread, fp16 weights.
//    One block per batch, 512 threads (8 waves), 1 block/CU.
//    Thread tid: q=tid&3 -> f-slice [128q,128q+128); rows (tid&~3)+0..3.
//    96 f/row in VGPRs (192 half2 regs), 32 f/row streamed from L2/L1.
//    h fp32 in LDS, q-slices padded to 132 floats (bank-conflict-free b128).
//    Quad butterfly (__shfl_xor 1,2) sums the 4 f-slices; thread tid owns
//    output g=tid exactly -> coalesced xw read / hout write. 1 barrier/step.
// ---------------------------------------------------------------------------
__global__ __launch_bounds__(512, 2)
void k_scan(const uint4* __restrict__ wp,   // this layer's [64][512] packs
            const float* __restrict__ xw,   // [NB*TB, FB] (includes bih)
            const float* __restrict__ bhh,  // [FB]
            float* __restrict__ hout)       // [NB*TB, FB]
{
    const int tid = threadIdx.x, b = blockIdx.x;
    const int q = tid & 3;
    __shared__ __align__(16) float hq[2][4][132];

    // register-resident weight packs: 48 uint4 = 192 VGPRs
    U4 wr[4][12];
    #pragma unroll
    for (int gi = 0; gi < 4; ++gi)
        #pragma unroll
        for (int k = 0; k < 12; ++k)
            wr[gi][k].u = wp[(gi * 12 + k) * 512 + tid];

    const float bg = bhh[tid];
    const uint4* wsp = wp + 48 * 512 + tid;   // stream packs base (16 per thread)

    hq[0][tid >> 7][tid & 127] = 0.f;
    __syncthreads();

    const float* xwb = xw   + (size_t)b * TB * FB;
    float*       hob = hout + (size_t)b * TB * FB;

    for (int t = 0; t < TB; ++t) {
        const float4* hs4 = (const float4*)&hq[t & 1][q][0];
        const float xwv = xwb[t * FB + tid];
        float acc[4] = {0.f, 0.f, 0.f, 0.f};

        // register part: f local [0,96)
        #pragma unroll
        for (int k = 0; k < 12; ++k) {
            const float4 ha = hs4[2 * k], hb = hs4[2 * k + 1];
            #pragma unroll
            for (int gi = 0; gi < 4; ++gi) {
                const U4 w = wr[gi][k];
                acc[gi] = fmaf(__low2float (w.h[0]), ha.x, acc[gi]);
                acc[gi] = fmaf(__high2float(w.h[0]), ha.y, acc[gi]);
                acc[gi] = fmaf(__low2float (w.h[1]), ha.z, acc[gi]);
                acc[gi] = fmaf(__high2float(w.h[1]), ha.w, acc[gi]);
                acc[gi] = fmaf(__low2float (w.h[2]), hb.x, acc[gi]);
                acc[gi] = fmaf(__high2float(w.h[2]), hb.y, acc[gi]);
                acc[gi] = fmaf(__low2float (w.h[3]), hb.z, acc[gi]);
                acc[gi] = fmaf(__high2float(w.h[3]), hb.w, acc[gi]);
            }
        }
        // streamed part: f local [96,128)  (same 16 uint4 every step -> L1)
        #pragma unroll
        for (int jp = 0; jp < 4; ++jp) {
            const float4 ha = hs4[24 + 2 * jp], hb = hs4[25 + 2 * jp];
            #pragma unroll
            for (int gi = 0; gi < 4; ++gi) {
                U4 w; w.u = wsp[(jp * 4 + gi) * 512];
                acc[gi] = fmaf(__low2float (w.h[0]), ha.x, acc[gi]);
                acc[gi] = fmaf(__high2float(w.h[0]), ha.y, acc[gi]);
                acc[gi] = fmaf(__low2float (w.h[1]), ha.z, acc[gi]);
                acc[gi] = fmaf(__high2float(w.h[1]), ha.w, acc[gi]);
                acc[gi] = fmaf(__low2float (w.h[2]), hb.x, acc[gi]);
                acc[gi] = fmaf(__high2float(w.h[2]), hb.y, acc[gi]);
                acc[gi] = fmaf(__low2float (w.h[3]), hb.z, acc[gi]);
                acc[gi] = fmaf(__high2float(w.h[3]), hb.w, acc[gi]);
            }
        }

        // quad butterfly: total over the 4 f-slices, all 4 lanes get all sums
        #pragma unroll
        for (int i = 0; i < 4; ++i) {
            acc[i] += __shfl_xor(acc[i], 1);
            acc[i] += __shfl_xor(acc[i], 2);
        }
        const float tot = (q == 0) ? acc[0] : (q == 1) ? acc[1]
                        : (q == 2) ? acc[2] : acc[3];

        const float hn = tanhf(tot + xwv + bg);
        hob[t * FB + tid] = hn;
        hq[(t + 1) & 1][tid >> 7][tid & 127] = hn;
        __syncthreads();
    }
}

// ---------------------------------------------------------------------------
// 4. Last-row spatio-temporal weights + weighted average (unchanged)
// ---------------------------------------------------------------------------
__global__ __launch_bounds__(512)
void k_wavg(const float* __restrict__ h2,
            const float* __restrict__ lat, const float* __restrict__ lon,
            const float* __restrict__ ut,  float* __restrict__ outs)
{
    const int b = blockIdx.x, tid = threadIdx.x;
    __shared__ float wv[TB];
    __shared__ float red[TB];

    const float p = 0.017453292519943295f;
    const size_t base = (size_t)b * TB;
    const float la_i = lat[base + TB - 1], lo_i = lon[base + TB - 1], ti = ut[base + TB - 1];
    const float la_j = lat[base + tid],    lo_j = lon[base + tid],    tj = ut[base + tid];

    float a = 0.5f - cosf((la_i - la_j) * p) * 0.5f
            + cosf(la_i * p) * cosf(la_j * p) * (1.0f - cosf((lo_i - lo_j) * p)) * 0.5f;
    a = fminf(fmaxf(a, 0.f), 1.f);
    const float dis = (a > 0.f) ? 12742.0f * asinf(sqrtf(a)) : 0.f;
    const float dt  = fabsf(ti - tj);
    const float w = (1.0f + cosf(6.2831853071795864769f * dt)) * 0.5f
                  * expf(-0.01f * dt) * expf(-100.0f * dis) + 1e-10f;

    wv[tid] = w; red[tid] = w;
    __syncthreads();
    for (int s = 256; s > 0; s >>= 1) {
        if (tid < s) red[tid] += red[tid + s];
        __syncthreads();
    }
    const float inv = 1.0f / red[0];

    float acc = 0.f;
    const float* hb = h2 + (size_t)b * TB * FB;
    for (int j = 0; j < TB; ++j) acc += wv[j] * hb[j * FB + tid];
    outs[(size_t)b * FB + tid] = acc * inv;
}

// ---------------------------------------------------------------------------
// kernel_launch
//   ws layout (floats): wp[2 layers * 64 * 512 uint4 = 262144 floats]
//                       | bufA[16.7M] | bufB[16.7M] | bufC[16.7M] | outs[64*512]
// ---------------------------------------------------------------------------
extern "C" void kernel_launch(void* const* d_in, const int* in_sizes, int n_in,
                              void* d_out, int out_size, void* d_ws, size_t ws_size,
                              hipStream_t stream)
{
    const int*   user = (const int*)d_in[0];
    const int*   poi  = (const int*)d_in[1];
    const float* lat  = (const float*)d_in[3];
    const float* lon  = (const float*)d_in[4];
    const float* ut   = (const float*)d_in[7];
    const float* utab = (const float*)d_in[8];
    const float* ptab = (const float*)d_in[9];
    const float* Wih  = (const float*)d_in[10];
    const float* Whh  = (const float*)d_in[11];
    const float* bih  = (const float*)d_in[12];
    const float* bhh  = (const float*)d_in[13];
    const float* Wlin = (const float*)d_in[14];
    const float* blin = (const float*)d_in[15];
    float* out = (float*)d_out;

    float* ws   = (float*)d_ws;
    const size_t big = (size_t)NB * TB * FB;        // 16,777,216
    uint4* wp   = (uint4*)ws;                       // 2*64*512 uint4 = 1 MiB
    float* bufA = ws + 2 * 64 * 512 * 4;            // 262144 floats after wp
    float* bufB = bufA + big;
    float* bufC = bufB + big;
    float* outs = bufC + big;                       // NB*FB

    // 1. pack Whh (both layers) into fp16 pack-slots
    k_pack<<<dim3(64, 2), 512, 0, stream>>>(Whh, wp);

    // 2. xw1 = (user_emb + poi_emb) @ Wih0^T + bih0 -> bufA
    k_gemm_bt<true, false><<<dim3(8, 512), 256, 0, stream>>>(
        nullptr, user, poi, utab, ptab, Wih, bih, bufA, nullptr,
        NB * TB, FB, FB);

    // 3. scan layer 0: bufA -> bufB
    k_scan<<<64, 512, 0, stream>>>(wp, bufA, bhh, bufB);

    // 4. xw2 = h1 @ Wih1^T + bih1 -> bufC
    k_gemm_bt<false, false><<<dim3(8, 512), 256, 0, stream>>>(
        bufB, nullptr, nullptr, nullptr, nullptr, Wih + FB * FB, bih + FB,
        bufC, nullptr, NB * TB, FB, FB);

    // 5. scan layer 1: bufC -> bufA
    k_scan<<<64, 512, 0, stream>>>(wp + 64 * 512, bufC, bhh + FB, bufA);

    // 6. last-row weighted average -> outs
    k_wavg<<<64, 512, 0, stream>>>(bufA, lat, lon, ut, outs);

    // 7. pre = outs @ W_lin^T + b_lin -> both tuple outputs
    k_gemm_bt<false, true><<<dim3((NPOI + 63) / 64, 1), 256, 0, stream>>>(
        outs, nullptr, nullptr, nullptr, nullptr, Wlin, blin,
        out, out + (size_t)NB * NPOI, NB, NPOI, FB);
}

// Round 7
// 43705.142 us; speedup vs baseline: 1.1556x; 1.1556x over previous
//
#include <hip/hip_runtime.h>
#include <hip/hip_fp16.h>
#include <cstddef>
#include <cstdint>

// Problem constants (from reference)
#define NB   64      // B
#define TB   512     // T
#define FB   512     // F
#define NPOI 100000

union U4 { uint4 u; __half2 h[4]; };

// ---------------------------------------------------------------------------
// 1. Pack Whh (fp32, [L][g][f]) into fp16 stream-packs for the scan.
//    Scan thread tid (of 1024): qi=tid>>2, q=tid&3; owns rows g=2qi,2qi+1 and
//    f-slice [128q,128q+128). Pack p = gi*16+k (gi in {0,1}, k in [0,16)):
//    wl[l][p][tid] = 8 consecutive halfs of W[2qi+gi][128q+8k .. +8].
//    Scan reads wl[p*1024+tid] -> perfectly coalesced 16 KB per p per block.
// ---------------------------------------------------------------------------
__global__ __launch_bounds__(1024)
void k_pack(const float* __restrict__ Whh, uint4* __restrict__ wl)
{
    const int p = blockIdx.x, l = blockIdx.y, tid = threadIdx.x;
    const int qi = tid >> 2, q = tid & 3;
    const int gi = p >> 4, k = p & 15;
    const int g = 2 * qi + gi;
    const int f = 128 * q + 8 * k;
    const float* src = Whh + (size_t)l * FB * FB + (size_t)g * FB + f;
    const float4 a = *(const float4*)src;
    const float4 b = *(const float4*)(src + 4);
    U4 o;
    o.h[0] = __floats2half2_rn(a.x, a.y);
    o.h[1] = __floats2half2_rn(a.z, a.w);
    o.h[2] = __floats2half2_rn(b.x, b.y);
    o.h[3] = __floats2half2_rn(b.z, b.w);
    wl[((size_t)l * 32 + p) * 1024 + tid] = o.u;
}

// ---------------------------------------------------------------------------
// 2. Generic fp32 GEMM: C[M,N] = A[M,K] @ B[N,K]^T + bias[N]  (unchanged)
// ---------------------------------------------------------------------------
template<bool EMBED, bool DUAL>
__global__ __launch_bounds__(256)
void k_gemm_bt(const float* __restrict__ A,
               const int* __restrict__ uidx, const int* __restrict__ pidx,
               const float* __restrict__ utab, const float* __restrict__ ptab,
               const float* __restrict__ Bm, const float* __restrict__ bias,
               float* __restrict__ C, float* __restrict__ C2,
               int M, int N, int K)
{
    __shared__ __align__(16) float As[16][68];
    __shared__ __align__(16) float Bs[16][68];
    __shared__ int us[64], ps[64];

    const int tid = threadIdx.x;
    const int tn  = tid & 15, tm = tid >> 4;
    const int m0  = blockIdx.y * 64, n0 = blockIdx.x * 64;
    const int lr  = tid >> 2;
    const int lc  = (tid & 3) * 4;

    if (EMBED) {
        if (tid < 64) { us[tid] = uidx[m0 + tid]; ps[tid] = pidx[m0 + tid]; }
        __syncthreads();
    }

    float acc[4][4] = {};

    for (int k0 = 0; k0 < K; k0 += 16) {
        float4 a4, b4;
        if (EMBED) {
            const float4 u4 = *(const float4*)&utab[(size_t)us[lr] * K + k0 + lc];
            const float4 p4 = *(const float4*)&ptab[(size_t)ps[lr] * K + k0 + lc];
            a4 = make_float4(u4.x + p4.x, u4.y + p4.y, u4.z + p4.z, u4.w + p4.w);
        } else {
            a4 = *(const float4*)&A[(size_t)(m0 + lr) * K + k0 + lc];
        }
        const int nr = n0 + lr;
        if (nr < N) b4 = *(const float4*)&Bm[(size_t)nr * K + k0 + lc];
        else        b4 = make_float4(0.f, 0.f, 0.f, 0.f);

        __syncthreads();
        As[lc + 0][lr] = a4.x; As[lc + 1][lr] = a4.y;
        As[lc + 2][lr] = a4.z; As[lc + 3][lr] = a4.w;
        Bs[lc + 0][lr] = b4.x; Bs[lc + 1][lr] = b4.y;
        Bs[lc + 2][lr] = b4.z; Bs[lc + 3][lr] = b4.w;
        __syncthreads();

        #pragma unroll
        for (int kk = 0; kk < 16; ++kk) {
            const float4 av4 = *(const float4*)&As[kk][tm * 4];
            const float4 bv4 = *(const float4*)&Bs[kk][tn * 4];
            const float av[4] = {av4.x, av4.y, av4.z, av4.w};
            const float bv[4] = {bv4.x, bv4.y, bv4.z, bv4.w};
            #pragma unroll
            for (int i = 0; i < 4; ++i)
                #pragma unroll
                for (int j = 0; j < 4; ++j)
                    acc[i][j] += av[i] * bv[j];
        }
    }

    const int cm = m0 + tm * 4, cn = n0 + tn * 4;
    #pragma unroll
    for (int i = 0; i < 4; ++i) {
        #pragma unroll
        for (int j = 0; j < 4; ++j) {
            const int n = cn + j;
            if (n < N) {
                const float v = acc[i][j] + bias[n];
                C[(size_t)(cm + i) * N + n] = v;
                if (DUAL) C2[(size_t)(cm + i) * N + n] = v;
            }
        }
    }
}

// ---------------------------------------------------------------------------
// 3. RNN scan, stream-all fp16 weights (NO loop-carried register arrays ->
//    nothing to spill; round-2/6 lesson). 1024 threads = 16 waves, 64 blocks.
//    Thread (qi=tid>>2, q=tid&3): rows g=2qi,2qi+1, f-slice [128q,128q+128).
//    Per step: 32 coalesced uint4 weight loads (L2-resident stream) +
//    32 broadcast ds_read_b128 of h + 512 fma (fma_mix-fusable) +
//    quad __shfl_xor reduce; lanes q<2 write h_new. 1 barrier/step.
// ---------------------------------------------------------------------------
__global__ __launch_bounds__(1024)
void k_scan(const uint4* __restrict__ wl,   // this layer's [32][1024] packs
            const float* __restrict__ xw,   // [NB*TB, FB]
            const float* __restrict__ bhh,  // [FB]
            float* __restrict__ hout)       // [NB*TB, FB]
{
    const int tid = threadIdx.x, b = blockIdx.x;
    const int qi = tid >> 2, q = tid & 3;
    __shared__ __align__(16) float hq[2][4][132];

    const int gw = 2 * qi + q;                    // writer's g (valid for q<2)
    const float bg = (q < 2) ? bhh[gw] : 0.f;

    if (tid < 512) hq[0][tid >> 7][tid & 127] = 0.f;
    __syncthreads();

    const float* xwb = xw   + (size_t)b * TB * FB;
    float*       hob = hout + (size_t)b * TB * FB;

    for (int t = 0; t < TB; ++t) {
        const float4* hs4 = (const float4*)&hq[t & 1][q][0];
        float xwv = 0.f;
        if (q < 2) xwv = xwb[t * FB + gw];        // issued early, used late
        float acc0 = 0.f, acc1 = 0.f;

        #pragma unroll
        for (int k = 0; k < 16; ++k) {
            const float4 ha = hs4[2 * k], hb4 = hs4[2 * k + 1];
            U4 w0; w0.u = wl[(size_t)(k)      * 1024 + tid];   // g = 2qi
            U4 w1; w1.u = wl[(size_t)(16 + k) * 1024 + tid];   // g = 2qi+1
            acc0 = fmaf(__low2float (w0.h[0]), ha.x,  acc0);
            acc0 = fmaf(__high2float(w0.h[0]), ha.y,  acc0);
            acc0 = fmaf(__low2float (w0.h[1]), ha.z,  acc0);
            acc0 = fmaf(__high2float(w0.h[1]), ha.w,  acc0);
            acc0 = fmaf(__low2float (w0.h[2]), hb4.x, acc0);
            acc0 = fmaf(__high2float(w0.h[2]), hb4.y, acc0);
            acc0 = fmaf(__low2float (w0.h[3]), hb4.z, acc0);
            acc0 = fmaf(__high2float(w0.h[3]), hb4.w, acc0);
            acc1 = fmaf(__low2float (w1.h[0]), ha.x,  acc1);
            acc1 = fmaf(__high2float(w1.h[0]), ha.y,  acc1);
            acc1 = fmaf(__low2float (w1.h[1]), ha.z,  acc1);
            acc1 = fmaf(__high2float(w1.h[1]), ha.w,  acc1);
            acc1 = fmaf(__low2float (w1.h[2]), hb4.x, acc1);
            acc1 = fmaf(__high2float(w1.h[2]), hb4.y, acc1);
            acc1 = fmaf(__low2float (w1.h[3]), hb4.z, acc1);
            acc1 = fmaf(__high2float(w1.h[3]), hb4.w, acc1);
        }

        // quad butterfly: every lane of the quad ends with both row sums
        acc0 += __shfl_xor(acc0, 1); acc0 += __shfl_xor(acc0, 2);
        acc1 += __shfl_xor(acc1, 1); acc1 += __shfl_xor(acc1, 2);

        if (q < 2) {
            const float s  = (q == 0) ? acc0 : acc1;
            const float hn = tanhf(s + xwv + bg);
            hob[t * FB + gw] = hn;
            hq[(t + 1) & 1][gw >> 7][gw & 127] = hn;
        }
        __syncthreads();
    }
}

// ---------------------------------------------------------------------------
// 4. Last-row spatio-temporal weights + weighted average (unchanged)
// ---------------------------------------------------------------------------
__global__ __launch_bounds__(512)
void k_wavg(const float* __restrict__ h2,
            const float* __restrict__ lat, const float* __restrict__ lon,
            const float* __restrict__ ut,  float* __restrict__ outs)
{
    const int b = blockIdx.x, tid = threadIdx.x;
    __shared__ float wv[TB];
    __shared__ float red[TB];

    const float p = 0.017453292519943295f;
    const size_t base = (size_t)b * TB;
    const float la_i = lat[base + TB - 1], lo_i = lon[base + TB - 1], ti = ut[base + TB - 1];
    const float la_j = lat[base + tid],    lo_j = lon[base + tid],    tj = ut[base + tid];

    float a = 0.5f - cosf((la_i - la_j) * p) * 0.5f
            + cosf(la_i * p) * cosf(la_j * p) * (1.0f - cosf((lo_i - lo_j) * p)) * 0.5f;
    a = fminf(fmaxf(a, 0.f), 1.f);
    const float dis = (a > 0.f) ? 12742.0f * asinf(sqrtf(a)) : 0.f;
    const float dt  = fabsf(ti - tj);
    const float w = (1.0f + cosf(6.2831853071795864769f * dt)) * 0.5f
                  * expf(-0.01f * dt) * expf(-100.0f * dis) + 1e-10f;

    wv[tid] = w; red[tid] = w;
    __syncthreads();
    for (int s = 256; s > 0; s >>= 1) {
        if (tid < s) red[tid] += red[tid + s];
        __syncthreads();
    }
    const float inv = 1.0f / red[0];

    float acc = 0.f;
    const float* hb = h2 + (size_t)b * TB * FB;
    for (int j = 0; j < TB; ++j) acc += wv[j] * hb[j * FB + tid];
    outs[(size_t)b * FB + tid] = acc * inv;
}

// ---------------------------------------------------------------------------
// kernel_launch
//   ws layout (floats): wl[2 layers * 32 * 1024 uint4 = 262144 floats = 1 MiB]
//                       | bufA[16.7M] | bufB[16.7M] | bufC[16.7M] | outs[64*512]
// ---------------------------------------------------------------------------
extern "C" void kernel_launch(void* const* d_in, const int* in_sizes, int n_in,
                              void* d_out, int out_size, void* d_ws, size_t ws_size,
                              hipStream_t stream)
{
    const int*   user = (const int*)d_in[0];
    const int*   poi  = (const int*)d_in[1];
    const float* lat  = (const float*)d_in[3];
    const float* lon  = (const float*)d_in[4];
    const float* ut   = (const float*)d_in[7];
    const float* utab = (const float*)d_in[8];
    const float* ptab = (const float*)d_in[9];
    const float* Wih  = (const float*)d_in[10];
    const float* Whh  = (const float*)d_in[11];
    const float* bih  = (const float*)d_in[12];
    const float* bhh  = (const float*)d_in[13];
    const float* Wlin = (const float*)d_in[14];
    const float* blin = (const float*)d_in[15];
    float* out = (float*)d_out;

    float* ws   = (float*)d_ws;
    const size_t big = (size_t)NB * TB * FB;        // 16,777,216
    uint4* wl   = (uint4*)ws;                       // 2*32*1024 uint4 = 1 MiB
    float* bufA = ws + 2 * 32 * 1024 * 4;           // 262144 floats after wl
    float* bufB = bufA + big;
    float* bufC = bufB + big;
    float* outs = bufC + big;                       // NB*FB

    // 1. pack Whh (both layers) into fp16 stream-packs
    k_pack<<<dim3(32, 2), 1024, 0, stream>>>(Whh, wl);

    // 2. xw1 = (user_emb + poi_emb) @ Wih0^T + bih0 -> bufA
    k_gemm_bt<true, false><<<dim3(8, 512), 256, 0, stream>>>(
        nullptr, user, poi, utab, ptab, Wih, bih, bufA, nullptr,
        NB * TB, FB, FB);

    // 3. scan layer 0: bufA -> bufB
    k_scan<<<64, 1024, 0, stream>>>(wl, bufA, bhh, bufB);

    // 4. xw2 = h1 @ Wih1^T + bih1 -> bufC
    k_gemm_bt<false, false><<<dim3(8, 512), 256, 0, stream>>>(
        bufB, nullptr, nullptr, nullptr, nullptr, Wih + FB * FB, bih + FB,
        bufC, nullptr, NB * TB, FB, FB);

    // 5. scan layer 1: bufC -> bufA
    k_scan<<<64, 1024, 0, stream>>>(wl + 32 * 1024, bufC, bhh + FB, bufA);

    // 6. last-row weighted average -> outs
    k_wavg<<<64, 512, 0, stream>>>(bufA, lat, lon, ut, outs);

    // 7. pre = outs @ W_lin^T + b_lin -> both tuple outputs
    k_gemm_bt<false, true><<<dim3((NPOI + 63) / 64, 1), 256, 0, stream>>>(
        outs, nullptr, nullptr, nullptr, nullptr, Wlin, blin,
        out, out + (size_t)NB * NPOI, NB, NPOI, FB);
}